// Round 12
// baseline (372.422 us; speedup 1.0000x reference)
//
#include <hip/hip_runtime.h>
#include <math.h>

#define N_USERS 100000
#define N_ITEMS 50000
#define NR      150000
#define N_EDGES 2000000
#define D       64
#define EPS     1e-12f

#define UPAD 48      // user bucket capacity (deg ~ Poisson(20); P(>48) ~ 1e-8)
#define IPAD 64      // item bucket capacity (deg ~ Poisson(40); few rows spill -> ovf)
#define OVF_CAP 4096

#define NPART 8      // XCDs (blockIdx % 8 lands on XCD p under round-robin dispatch)
#define UCH (N_USERS / NPART)   // 12500
#define ICH (N_ITEMS / NPART)   // 6250
#define FILL_BLOCKS 2048        // 256 blocks per XCD partition

// ---------------- workspace layout (bytes) ----------------
// scal : float4[NR]          @ 0             2,400,000   {invn, rsd, beta, rsd*norm}
// xh   : ushort[NR*64] (z!)  @ 2,400,000    19,200,000
// cnt  : int[NR]             @ 21,600,000      600,000
// ubkt : u16[N_USERS*48]     @ 22,200,000     9,600,000
// ibkt : u32[N_ITEMS*64]     @ 31,800,000    12,800,000
// ovfc : int (+pad)          @ 44,600,000            8
// ovf  : int2[OVF_CAP]       @ 44,600,008       32,768
#define SCAL_OFF 0u
#define XH_OFF   2400000u
#define CNT_OFF  21600000u
#define UBKT_OFF 22200000u
#define IBKT_OFF 31800000u
#define OVFC_OFF 44600000u
#define OVF_OFF  44600008u
#define WS_MAIN  44632776u

__device__ __forceinline__ unsigned short f2bf(float v) {
    unsigned int b = __float_as_uint(v);
    b += 0x7FFFu + ((b >> 16) & 1u);          // round-to-nearest-even
    return (unsigned short)(b >> 16);
}
#define BF_LO(w) __uint_as_float((w) << 16)
#define BF_HI(w) __uint_as_float((w) & 0xFFFF0000u)

// ---------------------------------------------------------------------------
// Prep: xh[r] = bf16(z_r)  (pre-normalized row);
//       scal[r] = { invn, rsd, beta_or_0, rsd*norm }
// ---------------------------------------------------------------------------
__global__ void prep_kernel(const float* __restrict__ x,
                            const float* __restrict__ beta,
                            const float* __restrict__ du,
                            const float* __restrict__ di,
                            float4* __restrict__ scal,
                            unsigned short* __restrict__ xh) {
    int gid  = blockIdx.x * blockDim.x + threadIdx.x;
    int r    = gid >> 6;
    int lane = gid & 63;
    if (r >= NR) return;

    float v  = x[r * D + lane];
    float ss = v * v;
    #pragma unroll
    for (int m = 32; m >= 1; m >>= 1) ss += __shfl_xor(ss, m);

    float nrm  = fmaxf(sqrtf(ss), EPS);
    float invn = 1.0f / nrm;
    xh[r * D + lane] = f2bf(v * invn);        // store z, not x

    if (lane == 0) {
        float deg = (r < N_USERS) ? du[r] : di[r - N_USERS];
        float bb  = (r < N_USERS) ? beta[r] : 0.0f;
        float rsd = rsqrtf(deg);
        scal[r] = make_float4(invn, rsd, bb, rsd * nrm);
    }
}

// ---------------------------------------------------------------------------
// XCD-partitioned bucket fill, NT-STORE variant.
// Bucket stores are write-once scattered data -> nontemporal stores bypass
// L2 allocation; partial lines merge in the memory-side Infinity Cache (the
// whole 22 MB bucket region is L3-resident), so dirty bucket lines are never
// refetched/re-evicted through L2. cnt atomics stay cached as before.
// XCD partitioning kept unchanged as the safety net (identical to round 11
// if nt is a no-op).
// ---------------------------------------------------------------------------
__global__ void fillx_kernel(const int* __restrict__ u,
                             const int* __restrict__ i,
                             int* __restrict__ cnt,
                             unsigned short* __restrict__ ubkt,
                             unsigned int* __restrict__ ibkt,
                             int* __restrict__ ovfc,
                             int2* __restrict__ ovf) {
    int p   = blockIdx.x & (NPART - 1);
    int qb  = blockIdx.x >> 3;
    int tid = qb * blockDim.x + threadIdx.x;
    const int stride = (FILL_BLOCKS / NPART) * 256;

    int ulo = p * UCH, uhi = ulo + UCH;
    int ilo = p * ICH, ihi = ilo + ICH;

    for (int e = tid; e < N_EDGES; e += stride) {
        int uu = __builtin_nontemporal_load(u + e);
        int ii = __builtin_nontemporal_load(i + e);

        if (uu >= ulo && uu < uhi) {
            int s = atomicAdd(&cnt[uu], 1);
            if (s < UPAD) {
                __builtin_nontemporal_store((unsigned short)ii,
                                            &ubkt[(size_t)uu * UPAD + s]);
            } else {
                int pp = atomicAdd(ovfc, 1);
                if (pp < OVF_CAP) ovf[pp] = make_int2(uu, N_USERS + ii);
            }
        }
        if (ii >= ilo && ii < ihi) {
            int s = atomicAdd(&cnt[N_USERS + ii], 1);
            if (s < IPAD) {
                __builtin_nontemporal_store((unsigned int)uu,
                                            &ibkt[(size_t)ii * IPAD + s]);
            } else {
                int pp = atomicAdd(ovfc, 1);
                if (pp < OVF_CAP) ovf[pp] = make_int2(N_USERS + ii, uu);
            }
        }
    }
}

// ---------------------------------------------------------------------------
// Gather USER rows: wave per row, 8 neighbors/iter, chase-free.
// lane = (g = lane>>3 slot, q = lane&7 dim octet). z pre-normalized:
// acc += (4*sig*(1-sig)*c_nbr) * z_nbr ; out = acc * rsd_own.
// ---------------------------------------------------------------------------
__global__ void gatherU_kernel(const unsigned short* __restrict__ xh,
                               const float4* __restrict__ scal,
                               const int* __restrict__ cnt,
                               const unsigned short* __restrict__ ubkt,
                               float* __restrict__ out) {
    int gid  = blockIdx.x * blockDim.x + threadIdx.x;
    int r    = gid >> 6;
    int lane = gid & 63;
    if (r >= N_USERS) return;

    int g = lane >> 3;
    int q = lane & 7;

    float4 sc = scal[r];
    uint4 hs = *(const uint4*)(xh + (size_t)r * D + q * 8);
    float xs0 = BF_LO(hs.x), xs1 = BF_HI(hs.x);
    float xs2 = BF_LO(hs.y), xs3 = BF_HI(hs.y);
    float xs4 = BF_LO(hs.z), xs5 = BF_HI(hs.z);
    float xs6 = BF_LO(hs.w), xs7 = BF_HI(hs.w);

    int deg = cnt[r];
    if (deg > UPAD) deg = UPAD;
    int iters = (deg + 7) >> 3;

    float a0=0.f,a1=0.f,a2=0.f,a3=0.f,a4=0.f,a5=0.f,a6=0.f,a7=0.f;

    for (int it = 0; it < iters; ++it) {
        int idx = it * 8 + g;
        bool valid = (idx < deg);
        int nb = N_USERS + (int)ubkt[(size_t)r * UPAD + (valid ? idx : 0)];

        float4 so = scal[nb];
        uint4 ho = *(const uint4*)(xh + (size_t)nb * D + q * 8);
        float o0 = BF_LO(ho.x), o1 = BF_HI(ho.x);
        float o2 = BF_LO(ho.y), o3 = BF_HI(ho.y);
        float o4 = BF_LO(ho.z), o5 = BF_HI(ho.z);
        float o6 = BF_LO(ho.w), o7 = BF_HI(ho.w);

        float pd = xs0*o0 + xs1*o1 + xs2*o2 + xs3*o3
                 + xs4*o4 + xs5*o5 + xs6*o6 + xs7*o7;
        pd += __shfl_xor(pd, 1);
        pd += __shfl_xor(pd, 2);
        pd += __shfl_xor(pd, 4);             // cosine (z pre-scaled)

        float sv  = pd - sc.z;               // own (user) beta
        float sig = 1.0f / (1.0f + __expf(-sv));
        float t4  = 4.0f * sig * (1.0f - sig) * so.w;   // * c_nbr
        t4 = valid ? t4 : 0.0f;

        a0 = fmaf(t4, o0, a0); a1 = fmaf(t4, o1, a1);
        a2 = fmaf(t4, o2, a2); a3 = fmaf(t4, o3, a3);
        a4 = fmaf(t4, o4, a4); a5 = fmaf(t4, o5, a5);
        a6 = fmaf(t4, o6, a6); a7 = fmaf(t4, o7, a7);
    }

    #pragma unroll
    for (int m = 8; m <= 32; m <<= 1) {
        a0 += __shfl_xor(a0, m); a1 += __shfl_xor(a1, m);
        a2 += __shfl_xor(a2, m); a3 += __shfl_xor(a3, m);
        a4 += __shfl_xor(a4, m); a5 += __shfl_xor(a5, m);
        a6 += __shfl_xor(a6, m); a7 += __shfl_xor(a7, m);
    }

    if (g == 0) {
        float rsd = sc.y;
        float4* o4p = (float4*)(out + (size_t)r * D + q * 8);
        o4p[0] = make_float4(a0*rsd, a1*rsd, a2*rsd, a3*rsd);
        o4p[1] = make_float4(a4*rsd, a5*rsd, a6*rsd, a7*rsd);
    }
}

// ---------------------------------------------------------------------------
// Gather ITEM rows (neighbor = user row; beta from the neighbor).
// ---------------------------------------------------------------------------
__global__ void gatherI_kernel(const unsigned short* __restrict__ xh,
                               const float4* __restrict__ scal,
                               const int* __restrict__ cnt,
                               const unsigned int* __restrict__ ibkt,
                               float* __restrict__ out) {
    int gid  = blockIdx.x * blockDim.x + threadIdx.x;
    int ri   = gid >> 6;
    int lane = gid & 63;
    if (ri >= N_ITEMS) return;
    int r = N_USERS + ri;

    int g = lane >> 3;
    int q = lane & 7;

    float4 sc = scal[r];
    uint4 hs = *(const uint4*)(xh + (size_t)r * D + q * 8);
    float xs0 = BF_LO(hs.x), xs1 = BF_HI(hs.x);
    float xs2 = BF_LO(hs.y), xs3 = BF_HI(hs.y);
    float xs4 = BF_LO(hs.z), xs5 = BF_HI(hs.z);
    float xs6 = BF_LO(hs.w), xs7 = BF_HI(hs.w);

    int deg = cnt[r];
    if (deg > IPAD) deg = IPAD;
    int iters = (deg + 7) >> 3;

    float a0=0.f,a1=0.f,a2=0.f,a3=0.f,a4=0.f,a5=0.f,a6=0.f,a7=0.f;

    for (int it = 0; it < iters; ++it) {
        int idx = it * 8 + g;
        bool valid = (idx < deg);
        int nb = (int)ibkt[(size_t)ri * IPAD + (valid ? idx : 0)];

        float4 so = scal[nb];
        uint4 ho = *(const uint4*)(xh + (size_t)nb * D + q * 8);
        float o0 = BF_LO(ho.x), o1 = BF_HI(ho.x);
        float o2 = BF_LO(ho.y), o3 = BF_HI(ho.y);
        float o4 = BF_LO(ho.z), o5 = BF_HI(ho.z);
        float o6 = BF_LO(ho.w), o7 = BF_HI(ho.w);

        float pd = xs0*o0 + xs1*o1 + xs2*o2 + xs3*o3
                 + xs4*o4 + xs5*o5 + xs6*o6 + xs7*o7;
        pd += __shfl_xor(pd, 1);
        pd += __shfl_xor(pd, 2);
        pd += __shfl_xor(pd, 4);

        float sv  = pd - so.z;               // neighbor (user) beta
        float sig = 1.0f / (1.0f + __expf(-sv));
        float t4  = 4.0f * sig * (1.0f - sig) * so.w;   // * c_nbr
        t4 = valid ? t4 : 0.0f;

        a0 = fmaf(t4, o0, a0); a1 = fmaf(t4, o1, a1);
        a2 = fmaf(t4, o2, a2); a3 = fmaf(t4, o3, a3);
        a4 = fmaf(t4, o4, a4); a5 = fmaf(t4, o5, a5);
        a6 = fmaf(t4, o6, a6); a7 = fmaf(t4, o7, a7);
    }

    #pragma unroll
    for (int m = 8; m <= 32; m <<= 1) {
        a0 += __shfl_xor(a0, m); a1 += __shfl_xor(a1, m);
        a2 += __shfl_xor(a2, m); a3 += __shfl_xor(a3, m);
        a4 += __shfl_xor(a4, m); a5 += __shfl_xor(a5, m);
        a6 += __shfl_xor(a6, m); a7 += __shfl_xor(a7, m);
    }

    if (g == 0) {
        float rsd = sc.y;
        float4* o4p = (float4*)(out + (size_t)r * D + q * 8);
        o4p[0] = make_float4(a0*rsd, a1*rsd, a2*rsd, a3*rsd);
        o4p[1] = make_float4(a4*rsd, a5*rsd, a6*rsd, a7*rsd);
    }
}

// ---------------------------------------------------------------------------
// Overflow fixer: (own_row, nbr_row); recompute in fp32, atomic-add own row.
// ---------------------------------------------------------------------------
__global__ void ovf2_kernel(const float* __restrict__ x,
                            const float4* __restrict__ scal,
                            const int* __restrict__ ovfc,
                            const int2* __restrict__ ovf,
                            float* __restrict__ out) {
    int n = *ovfc;
    if (n > OVF_CAP) n = OVF_CAP;
    int gid  = blockIdx.x * blockDim.x + threadIdx.x;
    int wave = gid >> 6, lane = gid & 63;
    int nw   = (gridDim.x * blockDim.x) >> 6;

    for (int k = wave; k < n; k += nw) {
        int d  = ovf[k].x;
        int nb = ovf[k].y;
        float xd = x[(size_t)d * D + lane];
        float xn = x[(size_t)nb * D + lane];
        float pd = xd * xn;
        #pragma unroll
        for (int m = 32; m >= 1; m >>= 1) pd += __shfl_xor(pd, m);
        float4 sd = scal[d];
        float4 sn = scal[nb];
        float sv  = pd * sd.x * sn.x - (sd.z + sn.z);   // one side's beta is 0
        float sig = 1.0f / (1.0f + __expf(-sv));
        float w   = 4.0f * sig * (1.0f - sig) * sd.y * sn.y;
        atomicAdd(&out[(size_t)d * D + lane], w * xn);
    }
}

// ---------------------------------------------------------------------------
// Tier-D fallback (round-1 proven atomics) for small workspace.
// ---------------------------------------------------------------------------
__global__ void norm_kernel(const float* __restrict__ x,
                            float* __restrict__ invn, int nrows) {
    int gid  = blockIdx.x * blockDim.x + threadIdx.x;
    int wave = gid >> 6, lane = gid & 63;
    if (wave >= nrows) return;
    float v  = x[wave * D + lane];
    float ss = v * v;
    #pragma unroll
    for (int m = 32; m >= 1; m >>= 1) ss += __shfl_xor(ss, m);
    if (lane == 0) invn[wave] = 1.0f / fmaxf(sqrtf(ss), EPS);
}

__global__ void edge_kernel(const float* __restrict__ x,
                            const float* __restrict__ beta,
                            const float* __restrict__ du,
                            const float* __restrict__ di,
                            const int* __restrict__ u,
                            const int* __restrict__ i,
                            const float* __restrict__ invn,
                            float* __restrict__ out) {
    int gid  = blockIdx.x * blockDim.x + threadIdx.x;
    int wave = gid >> 6, lane = gid & 63;
    if (wave >= N_EDGES) return;
    int uu = u[wave], ii = i[wave];
    float xu = x[uu * D + lane];
    float xi = x[(N_USERS + ii) * D + lane];
    float p = xu * xi;
    #pragma unroll
    for (int m = 32; m >= 1; m >>= 1) p += __shfl_xor(p, m);
    float s   = p * invn[uu] * invn[N_USERS + ii] - beta[uu];
    float sig = 1.0f / (1.0f + __expf(-s));
    float w   = 4.0f * sig * (1.0f - sig) * rsqrtf(du[uu]) * rsqrtf(di[ii]);
    atomicAdd(&out[uu * D + lane],             w * xi);
    atomicAdd(&out[(N_USERS + ii) * D + lane], w * xu);
}

// ---------------------------------------------------------------------------
extern "C" void kernel_launch(void* const* d_in, const int* in_sizes, int n_in,
                              void* d_out, int out_size, void* d_ws, size_t ws_size,
                              hipStream_t stream) {
    const float* x    = (const float*)d_in[0];
    const float* beta = (const float*)d_in[1];
    const float* du   = (const float*)d_in[2];
    const float* di   = (const float*)d_in[3];
    const int*   u    = (const int*)d_in[4];
    const int*   i    = (const int*)d_in[5];
    float* out = (float*)d_out;
    char*  ws  = (char*)d_ws;

    if (ws_size >= (size_t)WS_MAIN) {
        float4*         scal = (float4*)(ws + SCAL_OFF);
        unsigned short* xh   = (unsigned short*)(ws + XH_OFF);
        int*            cnt  = (int*)(ws + CNT_OFF);
        unsigned short* ubkt = (unsigned short*)(ws + UBKT_OFF);
        unsigned int*   ibkt = (unsigned int*)(ws + IBKT_OFF);
        int*            ovfc = (int*)(ws + OVFC_OFF);
        int2*           ovf  = (int2*)(ws + OVF_OFF);

        hipMemsetAsync(cnt, 0, (size_t)NR * sizeof(int), stream);
        hipMemsetAsync(ovfc, 0, sizeof(int), stream);
        prep_kernel<<<(NR + 3) / 4, 256, 0, stream>>>(x, beta, du, di, scal, xh);
        fillx_kernel<<<FILL_BLOCKS, 256, 0, stream>>>(u, i, cnt, ubkt, ibkt, ovfc, ovf);
        gatherU_kernel<<<(N_USERS + 3) / 4, 256, 0, stream>>>(xh, scal, cnt, ubkt, out);
        gatherI_kernel<<<(N_ITEMS + 3) / 4, 256, 0, stream>>>(xh, scal, cnt, ibkt, out);
        ovf2_kernel<<<64, 256, 0, stream>>>(x, scal, ovfc, ovf, out);
    } else {
        float* invn = (float*)ws;
        hipMemsetAsync(d_out, 0, (size_t)out_size * sizeof(float), stream);
        norm_kernel<<<(NR + 3) / 4, 256, 0, stream>>>(x, invn, NR);
        edge_kernel<<<(N_EDGES + 3) / 4, 256, 0, stream>>>(x, beta, du, di, u, i, invn, out);
    }
}

// Round 13
// 303.296 us; speedup vs baseline: 1.2279x; 1.2279x over previous
//
#include <hip/hip_runtime.h>
#include <math.h>

#define N_USERS 100000
#define N_ITEMS 50000
#define NR      150000
#define N_EDGES 2000000
#define D       64
#define EPS     1e-12f

#define UPAD 48      // user bucket capacity (deg ~ Poisson(20); P(>48) ~ 1e-8)
#define IPAD 64      // item bucket capacity (deg ~ Poisson(40); few rows spill -> ovf)
#define OVF_CAP 4096

#define NPART 8      // XCDs (blockIdx % 8 lands on XCD p under round-robin dispatch)
#define UCH (N_USERS / NPART)   // 12500
#define ICH (N_ITEMS / NPART)   // 6250
#define FILL_BLOCKS 2048        // 256 blocks per XCD partition

// ---------------- workspace layout (bytes) ----------------
// scal : float4[NR]          @ 0             2,400,000   {invn, rsd, beta, c=rsd*norm}
// xh   : ushort[NR*64] (z!)  @ 2,400,000    19,200,000
// cw   : float[NR]           @ 21,600,000      600,000   c only (gatherU nbr read, 4B)
// bc   : float2[NR]          @ 22,200,000    1,200,000   {beta, c} (gatherI nbr read, 8B)
// cnt  : int[NR]             @ 23,400,000      600,000
// ubkt : u16[N_USERS*48]     @ 24,000,000     9,600,000
// ibkt : u32[N_ITEMS*64]     @ 33,600,000    12,800,000
// ovfc : int (+pad)          @ 46,400,000            8
// ovf  : int2[OVF_CAP]       @ 46,400,008       32,768
#define SCAL_OFF 0u
#define XH_OFF   2400000u
#define CW_OFF   21600000u
#define BC_OFF   22200000u
#define CNT_OFF  23400000u
#define UBKT_OFF 24000000u
#define IBKT_OFF 33600000u
#define OVFC_OFF 46400000u
#define OVF_OFF  46400008u
#define WS_MAIN  46432776u

__device__ __forceinline__ unsigned short f2bf(float v) {
    unsigned int b = __float_as_uint(v);
    b += 0x7FFFu + ((b >> 16) & 1u);          // round-to-nearest-even
    return (unsigned short)(b >> 16);
}
#define BF_LO(w) __uint_as_float((w) << 16)
#define BF_HI(w) __uint_as_float((w) & 0xFFFF0000u)

// ---------------------------------------------------------------------------
// Prep, 16 lanes/row: float4 loads, 4-step shfl reduce, packed bf16 stores.
// xh[r] = bf16(z_r);  scal[r] = {invn, rsd, beta, c};  cw[r]=c;  bc[r]={beta,c}
// ---------------------------------------------------------------------------
__global__ void prep_kernel(const float* __restrict__ x,
                            const float* __restrict__ beta,
                            const float* __restrict__ du,
                            const float* __restrict__ di,
                            float4* __restrict__ scal,
                            unsigned short* __restrict__ xh,
                            float* __restrict__ cw,
                            float2* __restrict__ bc) {
    int gid = blockIdx.x * blockDim.x + threadIdx.x;
    int r   = gid >> 4;                 // 16 lanes per row
    int sl  = gid & 15;
    if (r >= NR) return;

    float4 v = *(const float4*)(x + (size_t)r * D + sl * 4);
    float ss = v.x*v.x + v.y*v.y + v.z*v.z + v.w*v.w;
    ss += __shfl_xor(ss, 1);
    ss += __shfl_xor(ss, 2);
    ss += __shfl_xor(ss, 4);
    ss += __shfl_xor(ss, 8);            // full row sum within 16-lane group

    float nrm  = fmaxf(sqrtf(ss), EPS);
    float invn = 1.0f / nrm;

    ushort4 st;
    st.x = f2bf(v.x * invn); st.y = f2bf(v.y * invn);
    st.z = f2bf(v.z * invn); st.w = f2bf(v.w * invn);
    *(ushort4*)(xh + (size_t)r * D + sl * 4) = st;     // 8B/lane, coalesced

    if (sl == 0) {
        float deg = (r < N_USERS) ? du[r] : di[r - N_USERS];
        float bb  = (r < N_USERS) ? beta[r] : 0.0f;
        float rsd = rsqrtf(deg);
        float c   = rsd * nrm;
        scal[r] = make_float4(invn, rsd, bb, c);
        cw[r]   = c;
        bc[r]   = make_float2(bb, c);
    }
}

// ---------------------------------------------------------------------------
// Round-6/11-proven XCD-partitioned bucket fill (plain cached stores; the
// nt-store variant was measured WORSE: 230us/256MB vs 174us/176MB).
// ---------------------------------------------------------------------------
__global__ void fillx_kernel(const int* __restrict__ u,
                             const int* __restrict__ i,
                             int* __restrict__ cnt,
                             unsigned short* __restrict__ ubkt,
                             unsigned int* __restrict__ ibkt,
                             int* __restrict__ ovfc,
                             int2* __restrict__ ovf) {
    int p   = blockIdx.x & (NPART - 1);
    int qb  = blockIdx.x >> 3;
    int tid = qb * blockDim.x + threadIdx.x;
    const int stride = (FILL_BLOCKS / NPART) * 256;

    int ulo = p * UCH, uhi = ulo + UCH;
    int ilo = p * ICH, ihi = ilo + ICH;

    for (int e = tid; e < N_EDGES; e += stride) {
        int uu = __builtin_nontemporal_load(u + e);
        int ii = __builtin_nontemporal_load(i + e);

        if (uu >= ulo && uu < uhi) {
            int s = atomicAdd(&cnt[uu], 1);
            if (s < UPAD) {
                ubkt[(size_t)uu * UPAD + s] = (unsigned short)ii;
            } else {
                int pp = atomicAdd(ovfc, 1);
                if (pp < OVF_CAP) ovf[pp] = make_int2(uu, N_USERS + ii);
            }
        }
        if (ii >= ilo && ii < ihi) {
            int s = atomicAdd(&cnt[N_USERS + ii], 1);
            if (s < IPAD) {
                ibkt[(size_t)ii * IPAD + s] = (unsigned int)uu;
            } else {
                int pp = atomicAdd(ovfc, 1);
                if (pp < OVF_CAP) ovf[pp] = make_int2(N_USERS + ii, uu);
            }
        }
    }
}

// ---------------------------------------------------------------------------
// Gather USER rows: wave per row, 8 neighbors/iter, chase-free.
// Neighbor scalar read is 4B (cw). Sigmoid via exp + fast rcp (no IEEE div):
// w = 4 q r^2 c  with q = e^{-s}, r = rcp(1+q).  |s| <= ~2 -> no overflow.
// ---------------------------------------------------------------------------
__global__ void gatherU_kernel(const unsigned short* __restrict__ xh,
                               const float4* __restrict__ scal,
                               const int* __restrict__ cnt,
                               const unsigned short* __restrict__ ubkt,
                               const float* __restrict__ cw,
                               float* __restrict__ out) {
    int gid  = blockIdx.x * blockDim.x + threadIdx.x;
    int r    = gid >> 6;
    int lane = gid & 63;
    if (r >= N_USERS) return;

    int g = lane >> 3;
    int q = lane & 7;

    float4 sc = scal[r];
    uint4 hs = *(const uint4*)(xh + (size_t)r * D + q * 8);
    float xs0 = BF_LO(hs.x), xs1 = BF_HI(hs.x);
    float xs2 = BF_LO(hs.y), xs3 = BF_HI(hs.y);
    float xs4 = BF_LO(hs.z), xs5 = BF_HI(hs.z);
    float xs6 = BF_LO(hs.w), xs7 = BF_HI(hs.w);

    int deg = cnt[r];
    if (deg > UPAD) deg = UPAD;
    int iters = (deg + 7) >> 3;

    float a0=0.f,a1=0.f,a2=0.f,a3=0.f,a4=0.f,a5=0.f,a6=0.f,a7=0.f;

    for (int it = 0; it < iters; ++it) {
        int idx = it * 8 + g;
        bool valid = (idx < deg);
        int nb = N_USERS + (int)ubkt[(size_t)r * UPAD + (valid ? idx : 0)];

        float cn = cw[nb];
        uint4 ho = *(const uint4*)(xh + (size_t)nb * D + q * 8);
        float o0 = BF_LO(ho.x), o1 = BF_HI(ho.x);
        float o2 = BF_LO(ho.y), o3 = BF_HI(ho.y);
        float o4 = BF_LO(ho.z), o5 = BF_HI(ho.z);
        float o6 = BF_LO(ho.w), o7 = BF_HI(ho.w);

        float pd = xs0*o0 + xs1*o1 + xs2*o2 + xs3*o3
                 + xs4*o4 + xs5*o5 + xs6*o6 + xs7*o7;
        pd += __shfl_xor(pd, 1);
        pd += __shfl_xor(pd, 2);
        pd += __shfl_xor(pd, 4);             // cosine (z pre-scaled)

        float sv = pd - sc.z;                // own (user) beta
        float qe = __expf(-sv);
        float rr = __builtin_amdgcn_rcpf(1.0f + qe);
        float t4 = 4.0f * qe * rr * rr * cn;
        t4 = valid ? t4 : 0.0f;

        a0 = fmaf(t4, o0, a0); a1 = fmaf(t4, o1, a1);
        a2 = fmaf(t4, o2, a2); a3 = fmaf(t4, o3, a3);
        a4 = fmaf(t4, o4, a4); a5 = fmaf(t4, o5, a5);
        a6 = fmaf(t4, o6, a6); a7 = fmaf(t4, o7, a7);
    }

    #pragma unroll
    for (int m = 8; m <= 32; m <<= 1) {
        a0 += __shfl_xor(a0, m); a1 += __shfl_xor(a1, m);
        a2 += __shfl_xor(a2, m); a3 += __shfl_xor(a3, m);
        a4 += __shfl_xor(a4, m); a5 += __shfl_xor(a5, m);
        a6 += __shfl_xor(a6, m); a7 += __shfl_xor(a7, m);
    }

    if (g == 0) {
        float rsd = sc.y;
        float4* o4p = (float4*)(out + (size_t)r * D + q * 8);
        o4p[0] = make_float4(a0*rsd, a1*rsd, a2*rsd, a3*rsd);
        o4p[1] = make_float4(a4*rsd, a5*rsd, a6*rsd, a7*rsd);
    }
}

// ---------------------------------------------------------------------------
// Gather ITEM rows (neighbor = user row; beta from neighbor). 8B bc read.
// ---------------------------------------------------------------------------
__global__ void gatherI_kernel(const unsigned short* __restrict__ xh,
                               const float4* __restrict__ scal,
                               const int* __restrict__ cnt,
                               const unsigned int* __restrict__ ibkt,
                               const float2* __restrict__ bc,
                               float* __restrict__ out) {
    int gid  = blockIdx.x * blockDim.x + threadIdx.x;
    int ri   = gid >> 6;
    int lane = gid & 63;
    if (ri >= N_ITEMS) return;
    int r = N_USERS + ri;

    int g = lane >> 3;
    int q = lane & 7;

    float4 sc = scal[r];
    uint4 hs = *(const uint4*)(xh + (size_t)r * D + q * 8);
    float xs0 = BF_LO(hs.x), xs1 = BF_HI(hs.x);
    float xs2 = BF_LO(hs.y), xs3 = BF_HI(hs.y);
    float xs4 = BF_LO(hs.z), xs5 = BF_HI(hs.z);
    float xs6 = BF_LO(hs.w), xs7 = BF_HI(hs.w);

    int deg = cnt[r];
    if (deg > IPAD) deg = IPAD;
    int iters = (deg + 7) >> 3;

    float a0=0.f,a1=0.f,a2=0.f,a3=0.f,a4=0.f,a5=0.f,a6=0.f,a7=0.f;

    for (int it = 0; it < iters; ++it) {
        int idx = it * 8 + g;
        bool valid = (idx < deg);
        int nb = (int)ibkt[(size_t)ri * IPAD + (valid ? idx : 0)];

        float2 so2 = bc[nb];                 // {beta_u, c_u}
        uint4 ho = *(const uint4*)(xh + (size_t)nb * D + q * 8);
        float o0 = BF_LO(ho.x), o1 = BF_HI(ho.x);
        float o2 = BF_LO(ho.y), o3 = BF_HI(ho.y);
        float o4 = BF_LO(ho.z), o5 = BF_HI(ho.z);
        float o6 = BF_LO(ho.w), o7 = BF_HI(ho.w);

        float pd = xs0*o0 + xs1*o1 + xs2*o2 + xs3*o3
                 + xs4*o4 + xs5*o5 + xs6*o6 + xs7*o7;
        pd += __shfl_xor(pd, 1);
        pd += __shfl_xor(pd, 2);
        pd += __shfl_xor(pd, 4);

        float sv = pd - so2.x;               // neighbor (user) beta
        float qe = __expf(-sv);
        float rr = __builtin_amdgcn_rcpf(1.0f + qe);
        float t4 = 4.0f * qe * rr * rr * so2.y;
        t4 = valid ? t4 : 0.0f;

        a0 = fmaf(t4, o0, a0); a1 = fmaf(t4, o1, a1);
        a2 = fmaf(t4, o2, a2); a3 = fmaf(t4, o3, a3);
        a4 = fmaf(t4, o4, a4); a5 = fmaf(t4, o5, a5);
        a6 = fmaf(t4, o6, a6); a7 = fmaf(t4, o7, a7);
    }

    #pragma unroll
    for (int m = 8; m <= 32; m <<= 1) {
        a0 += __shfl_xor(a0, m); a1 += __shfl_xor(a1, m);
        a2 += __shfl_xor(a2, m); a3 += __shfl_xor(a3, m);
        a4 += __shfl_xor(a4, m); a5 += __shfl_xor(a5, m);
        a6 += __shfl_xor(a6, m); a7 += __shfl_xor(a7, m);
    }

    if (g == 0) {
        float rsd = sc.y;
        float4* o4p = (float4*)(out + (size_t)r * D + q * 8);
        o4p[0] = make_float4(a0*rsd, a1*rsd, a2*rsd, a3*rsd);
        o4p[1] = make_float4(a4*rsd, a5*rsd, a6*rsd, a7*rsd);
    }
}

// ---------------------------------------------------------------------------
// Overflow fixer: (own_row, nbr_row); recompute in fp32, atomic-add own row.
// ---------------------------------------------------------------------------
__global__ void ovf2_kernel(const float* __restrict__ x,
                            const float4* __restrict__ scal,
                            const int* __restrict__ ovfc,
                            const int2* __restrict__ ovf,
                            float* __restrict__ out) {
    int n = *ovfc;
    if (n > OVF_CAP) n = OVF_CAP;
    int gid  = blockIdx.x * blockDim.x + threadIdx.x;
    int wave = gid >> 6, lane = gid & 63;
    int nw   = (gridDim.x * blockDim.x) >> 6;

    for (int k = wave; k < n; k += nw) {
        int d  = ovf[k].x;
        int nb = ovf[k].y;
        float xd = x[(size_t)d * D + lane];
        float xn = x[(size_t)nb * D + lane];
        float pd = xd * xn;
        #pragma unroll
        for (int m = 32; m >= 1; m >>= 1) pd += __shfl_xor(pd, m);
        float4 sd = scal[d];
        float4 sn = scal[nb];
        float sv  = pd * sd.x * sn.x - (sd.z + sn.z);   // one side's beta is 0
        float sig = 1.0f / (1.0f + __expf(-sv));
        float w   = 4.0f * sig * (1.0f - sig) * sd.y * sn.y;
        atomicAdd(&out[(size_t)d * D + lane], w * xn);
    }
}

// ---------------------------------------------------------------------------
// Tier-D fallback (round-1 proven atomics) for small workspace.
// ---------------------------------------------------------------------------
__global__ void norm_kernel(const float* __restrict__ x,
                            float* __restrict__ invn, int nrows) {
    int gid  = blockIdx.x * blockDim.x + threadIdx.x;
    int wave = gid >> 6, lane = gid & 63;
    if (wave >= nrows) return;
    float v  = x[wave * D + lane];
    float ss = v * v;
    #pragma unroll
    for (int m = 32; m >= 1; m >>= 1) ss += __shfl_xor(ss, m);
    if (lane == 0) invn[wave] = 1.0f / fmaxf(sqrtf(ss), EPS);
}

__global__ void edge_kernel(const float* __restrict__ x,
                            const float* __restrict__ beta,
                            const float* __restrict__ du,
                            const float* __restrict__ di,
                            const int* __restrict__ u,
                            const int* __restrict__ i,
                            const float* __restrict__ invn,
                            float* __restrict__ out) {
    int gid  = blockIdx.x * blockDim.x + threadIdx.x;
    int wave = gid >> 6, lane = gid & 63;
    if (wave >= N_EDGES) return;
    int uu = u[wave], ii = i[wave];
    float xu = x[uu * D + lane];
    float xi = x[(N_USERS + ii) * D + lane];
    float p = xu * xi;
    #pragma unroll
    for (int m = 32; m >= 1; m >>= 1) p += __shfl_xor(p, m);
    float s   = p * invn[uu] * invn[N_USERS + ii] - beta[uu];
    float sig = 1.0f / (1.0f + __expf(-s));
    float w   = 4.0f * sig * (1.0f - sig) * rsqrtf(du[uu]) * rsqrtf(di[ii]);
    atomicAdd(&out[uu * D + lane],             w * xi);
    atomicAdd(&out[(N_USERS + ii) * D + lane], w * xu);
}

// ---------------------------------------------------------------------------
extern "C" void kernel_launch(void* const* d_in, const int* in_sizes, int n_in,
                              void* d_out, int out_size, void* d_ws, size_t ws_size,
                              hipStream_t stream) {
    const float* x    = (const float*)d_in[0];
    const float* beta = (const float*)d_in[1];
    const float* du   = (const float*)d_in[2];
    const float* di   = (const float*)d_in[3];
    const int*   u    = (const int*)d_in[4];
    const int*   i    = (const int*)d_in[5];
    float* out = (float*)d_out;
    char*  ws  = (char*)d_ws;

    if (ws_size >= (size_t)WS_MAIN) {
        float4*         scal = (float4*)(ws + SCAL_OFF);
        unsigned short* xh   = (unsigned short*)(ws + XH_OFF);
        float*          cw   = (float*)(ws + CW_OFF);
        float2*         bc   = (float2*)(ws + BC_OFF);
        int*            cnt  = (int*)(ws + CNT_OFF);
        unsigned short* ubkt = (unsigned short*)(ws + UBKT_OFF);
        unsigned int*   ibkt = (unsigned int*)(ws + IBKT_OFF);
        int*            ovfc = (int*)(ws + OVFC_OFF);
        int2*           ovf  = (int2*)(ws + OVF_OFF);

        hipMemsetAsync(cnt, 0, (size_t)NR * sizeof(int), stream);
        hipMemsetAsync(ovfc, 0, sizeof(int), stream);
        prep_kernel<<<(NR * 16 + 255) / 256, 256, 0, stream>>>(
            x, beta, du, di, scal, xh, cw, bc);
        fillx_kernel<<<FILL_BLOCKS, 256, 0, stream>>>(u, i, cnt, ubkt, ibkt, ovfc, ovf);
        gatherU_kernel<<<(N_USERS + 3) / 4, 256, 0, stream>>>(xh, scal, cnt, ubkt, cw, out);
        gatherI_kernel<<<(N_ITEMS + 3) / 4, 256, 0, stream>>>(xh, scal, cnt, ibkt, bc, out);
        ovf2_kernel<<<64, 256, 0, stream>>>(x, scal, ovfc, ovf, out);
    } else {
        float* invn = (float*)ws;
        hipMemsetAsync(d_out, 0, (size_t)out_size * sizeof(float), stream);
        norm_kernel<<<(NR + 3) / 4, 256, 0, stream>>>(x, invn, NR);
        edge_kernel<<<(N_EDGES + 3) / 4, 256, 0, stream>>>(x, beta, du, di, u, i, invn, out);
    }
}